// Round 5
// baseline (740.951 us; speedup 1.0000x reference)
//
#include <hip/hip_runtime.h>
#include <math.h>

typedef unsigned short u16;
typedef __attribute__((ext_vector_type(8))) short bf16x8;
typedef __attribute__((ext_vector_type(4))) float f32x4;

#define S_N 16384
#define Q_N 4096
#define D_N 1024
#define C_N 256
#define NS 8
#define BQ 128
#define BS 256
#define BK 64
#define SRANGE (S_N / NS)     // 2048
#define NTILES (SRANGE / BS)  // 8
#define NKC (D_N / BK)        // 16
#define NTHR 512

// ---- workspace layout (bytes) ----
#define WS_MASSP   0u                                    // Q*C*4 = 4 MB
#define WS_MU      (WS_MASSP + 4194304u)                 // D*4
#define WS_COUNTS  (WS_MU + 4096u)                       // C*4
#define WS_NORMS   (WS_COUNTS + 1024u)                   // S*4
#define WS_COLPART (WS_NORMS + 65536u)                   // 1024*D*4 = 4 MB
#define WS_SUPPB   (WS_COLPART + 4194304u)               // S*D*2 = 32 MB
#define WS_QB      (WS_SUPPB + 33554432u)                // Q*D*2 = 8 MB

#define GLOAD16(g, l)                                                        \
    __builtin_amdgcn_global_load_lds(                                        \
        (const __attribute__((address_space(1))) void*)(g),                  \
        (__attribute__((address_space(3))) void*)(l), 16, 0, 0)

__device__ __forceinline__ u16 f2bf(float f) {
    unsigned x = __float_as_uint(f);
    return (u16)((x + 0x7fffu + ((x >> 16) & 1u)) >> 16);
}

__device__ __forceinline__ float blkSum(float v, float* sh) {
#pragma unroll
    for (int o = 32; o; o >>= 1) v += __shfl_down(v, o);
    if ((threadIdx.x & 63) == 0) sh[threadIdx.x >> 6] = v;
    __syncthreads();
    float r = sh[0] + sh[1] + sh[2] + sh[3];
    __syncthreads();
    return r;
}

__device__ __forceinline__ float blkMax(float v, float* sh) {
#pragma unroll
    for (int o = 32; o; o >>= 1) v = fmaxf(v, __shfl_down(v, o));
    if ((threadIdx.x & 63) == 0) sh[threadIdx.x >> 6] = v;
    __syncthreads();
    float r = fmaxf(fmaxf(sh[0], sh[1]), fmaxf(sh[2], sh[3]));
    __syncthreads();
    return r;
}

// ---- fused: row norms + column partial sums of normalized rows + label counts ----
// 256 blocks x 256 thr; block handles 64 rows; wave handles 16 rows
__global__ void k_prep(const float* __restrict__ sup, const int* __restrict__ lab,
                       float* __restrict__ colpart, float* __restrict__ norms,
                       int* __restrict__ counts) {
    int t = threadIdx.x, w = t >> 6, lane = t & 63;
    int r0 = blockIdx.x * 64;
    float acc[16];
#pragma unroll
    for (int i = 0; i < 16; i++) acc[i] = 0.f;
    for (int rr = 0; rr < 16; ++rr) {
        int r = r0 + w * 16 + rr;
        const float4* rp = (const float4*)(sup + (size_t)r * D_N);
        float4 v[4];
        float ss = 0.f;
#pragma unroll
        for (int i = 0; i < 4; i++) {
            v[i] = rp[lane + 64 * i];
            ss += v[i].x * v[i].x + v[i].y * v[i].y + v[i].z * v[i].z + v[i].w * v[i].w;
        }
#pragma unroll
        for (int o = 32; o; o >>= 1) ss += __shfl_xor(ss, o);
        float n = sqrtf(ss);
        if (lane == 0) norms[r] = n;
        float inv = 1.f / fmaxf(n, 1e-8f);
#pragma unroll
        for (int i = 0; i < 4; i++) {
            acc[4 * i + 0] += v[i].x * inv;
            acc[4 * i + 1] += v[i].y * inv;
            acc[4 * i + 2] += v[i].z * inv;
            acc[4 * i + 3] += v[i].w * inv;
        }
    }
    float4* cp = (float4*)(colpart + ((size_t)blockIdx.x * 4 + w) * D_N);
#pragma unroll
    for (int i = 0; i < 4; i++)
        cp[lane + 64 * i] = make_float4(acc[4 * i], acc[4 * i + 1], acc[4 * i + 2], acc[4 * i + 3]);
    if (t < 64) atomicAdd(&counts[lab[r0 + t]], 1);
}

// ---- reduce 1024 partials -> mu ----
__global__ void k_mu(const float* __restrict__ colpart, float* __restrict__ mu) {
    int c = blockIdx.x * 256 + threadIdx.x;
    float s = 0.f;
#pragma unroll 8
    for (int i = 0; i < 1024; i++) s += colpart[(size_t)i * D_N + c];
    mu[c] = s * (1.f / (float)S_N);
}

// ---- support: normalize, center, renormalize, -> bf16 ----
__global__ void k_suptrans(const float* __restrict__ sup, const float* __restrict__ norms,
                           const float* __restrict__ mu, u16* __restrict__ outb) {
    __shared__ float sh[4];
    int r = blockIdx.x, t = threadIdx.x;
    float inv = 1.f / fmaxf(norms[r], 1e-8f);
    float4 x = ((const float4*)(sup + (size_t)r * D_N))[t];
    float4 m = ((const float4*)mu)[t];
    float4 y;
    y.x = x.x * inv - m.x; y.y = x.y * inv - m.y;
    y.z = x.z * inv - m.z; y.w = x.w * inv - m.w;
    float ss = y.x * y.x + y.y * y.y + y.z * y.z + y.w * y.w;
    float tot = blkSum(ss, sh);
    float inv2 = 1.f / fmaxf(sqrtf(tot), 1e-8f);
    ushort4 u;
    u.x = f2bf(y.x * inv2); u.y = f2bf(y.y * inv2);
    u.z = f2bf(y.z * inv2); u.w = f2bf(y.w * inv2);
    ((ushort4*)(outb + (size_t)r * D_N))[t] = u;
}

// ---- query: normalize, center, renormalize, -> bf16 ----
__global__ void k_qtrans(const float* __restrict__ qry, const float* __restrict__ mu,
                         u16* __restrict__ outb) {
    __shared__ float sh[4];
    int r = blockIdx.x, t = threadIdx.x;
    float4 x = ((const float4*)(qry + (size_t)r * D_N))[t];
    float ss1 = x.x * x.x + x.y * x.y + x.z * x.z + x.w * x.w;
    float tot1 = blkSum(ss1, sh);
    float inv1 = 1.f / fmaxf(sqrtf(tot1), 1e-8f);
    float4 m = ((const float4*)mu)[t];
    float4 y;
    y.x = x.x * inv1 - m.x; y.y = x.y * inv1 - m.y;
    y.z = x.z * inv1 - m.z; y.w = x.w * inv1 - m.w;
    float ss2 = y.x * y.x + y.y * y.y + y.z * y.z + y.w * y.w;
    float tot2 = blkSum(ss2, sh);
    float inv2 = 1.f / fmaxf(sqrtf(tot2), 1e-8f);
    ushort4 u;
    u.x = f2bf(y.x * inv2); u.y = f2bf(y.y * inv2);
    u.z = f2bf(y.z * inv2); u.w = f2bf(y.w * inv2);
    ((ushort4*)(outb + (size_t)r * D_N))[t] = u;
}

// ---- main: pipelined sims-GEMM (128x256 tile, 64x64/wave) + exp + mass-GEMM ----
__launch_bounds__(NTHR, 2)
__global__ void k_mass(const u16* __restrict__ Qb, const u16* __restrict__ Sb,
                       const int* __restrict__ lab, const float* __restrict__ scale_p,
                       float* __restrict__ massp) {
    __shared__ u16 sQ[2][BQ * BK];    // 2x16 KB
    __shared__ u16 sS[2][BS * BK];    // 2x32 KB
    __shared__ u16 sP[BQ * 128];      // 32 KB, exp(P) bf16 for one s-half, swizzled
    __shared__ int slabAll[SRANGE];   // 8 KB

    const int t = threadIdx.x;
    const int lane = t & 63, w = t >> 6;
    const int wrow = w >> 2, wcol = w & 3;      // sims wave grid 2x4, 64x64 per wave
    const int l15 = lane & 15, l4 = lane >> 4;
    const int sblk = blockIdx.x & 7;            // XCD-exact: all blocks of an s-range on one XCD
    const int qblk = blockIdx.x >> 3;
    const int qbase = qblk * BQ;
    const int s0 = sblk * SRANGE;

    const float scale = fminf(fmaxf(*scale_p, 1.f), 20.f);
    const float sl2 = scale * 1.44269504f;

    // staging: thread t stages LDS byte t*16 (linear); global source chunk pre-swizzled
    const int srow = t >> 3;
    const int gck = (t & 7) ^ (srow & 7);
    const int lofs = w * 1024;

    // sims fragment read offsets: XOR swizzle within 128B row
    int aoff[4][2], boff[4][2];
#pragma unroll
    for (int m = 0; m < 4; m++)
#pragma unroll
        for (int k2 = 0; k2 < 2; k2++) {
            int r = wrow * 64 + m * 16 + l15;
            aoff[m][k2] = r * 128 + ((k2 * 64 + l4 * 16) ^ ((r & 7) << 4));
        }
#pragma unroll
    for (int n = 0; n < 4; n++)
#pragma unroll
        for (int k2 = 0; k2 < 2; k2++) {
            int r = wcol * 64 + n * 16 + l15;
            boff[n][k2] = r * 128 + ((k2 * 64 + l4 * 16) ^ ((r & 7) << 4));
        }

    auto stage = [&](int sbase, int kc, int buf) {
        const u16* gq = Qb + (size_t)(qbase + srow) * D_N + kc * BK + gck * 8;
        const u16* gs = Sb + (size_t)(sbase + srow) * D_N + kc * BK + gck * 8;
        char* lq = (char*)sQ[buf] + lofs;
        char* ls = (char*)sS[buf] + lofs;
        GLOAD16(gq, lq);
        GLOAD16(gq + 64 * D_N, lq + 8192);
        GLOAD16(gs, ls);
        GLOAD16(gs + 64 * D_N, ls + 8192);
        GLOAD16(gs + 128 * D_N, ls + 16384);
        GLOAD16(gs + 192 * D_N, ls + 24576);
    };

    // slab first, then clean drain so pipeline vmcnt counts are exact
    for (int i = t; i < SRANGE; i += NTHR) slabAll[i] = lab[s0 + i];
    asm volatile("s_waitcnt vmcnt(0) lgkmcnt(0)" ::: "memory");
    __builtin_amdgcn_s_barrier();

    // mass accumulator: wave covers (h*64 q-rows) x (64 c-cols)
    const int h = w >> 2;
    const int c0 = (w & 3) * 64;
    f32x4 macc[4][4];
#pragma unroll
    for (int m = 0; m < 4; m++)
#pragma unroll
        for (int n = 0; n < 4; n++) macc[m][n] = (f32x4){0.f, 0.f, 0.f, 0.f};

    stage(s0, 0, 0);   // prologue

    for (int st = 0; st < NTILES; ++st) {
        const int sbase = s0 + st * BS;
        f32x4 acc[4][4];
#pragma unroll
        for (int m = 0; m < 4; m++)
#pragma unroll
            for (int n = 0; n < 4; n++) acc[m][n] = (f32x4){0.f, 0.f, 0.f, 0.f};

        for (int kc = 0; kc < NKC; ++kc) {
            const int buf = kc & 1;
            int nkc = kc + 1, nsb = sbase;
            if (nkc == NKC) { nkc = 0; nsb = (st + 1 < NTILES) ? sbase + BS : sbase; }
            stage(nsb, nkc, buf ^ 1);
            asm volatile("s_waitcnt vmcnt(6)" ::: "memory");  // current chunk resident
            __builtin_amdgcn_s_barrier();
            __builtin_amdgcn_sched_barrier(0);

            const char* bq = (const char*)sQ[buf];
            const char* bs = (const char*)sS[buf];
            __builtin_amdgcn_s_setprio(1);
#pragma unroll
            for (int k2 = 0; k2 < 2; k2++) {
                bf16x8 a[4], b[4];
#pragma unroll
                for (int m = 0; m < 4; m++) a[m] = *(const bf16x8*)(bq + aoff[m][k2]);
#pragma unroll
                for (int n = 0; n < 4; n++) b[n] = *(const bf16x8*)(bs + boff[n][k2]);
#pragma unroll
                for (int m = 0; m < 4; m++)
#pragma unroll
                    for (int n = 0; n < 4; n++)
                        acc[m][n] = __builtin_amdgcn_mfma_f32_16x16x32_bf16(a[m], b[n], acc[m][n], 0, 0, 0);
            }
            __builtin_amdgcn_s_setprio(0);
            __builtin_amdgcn_sched_barrier(0);
            __builtin_amdgcn_s_barrier();   // readers done; buf becomes prefetch target
        }

        // ---- epilogue: two s-half passes (sP = 128q x 128s bf16, swizzled) ----
#pragma unroll
        for (int hf = 0; hf < 2; ++hf) {
            if ((wcol >> 1) == hf) {   // waves owning this s-half write exp(P)
#pragma unroll
                for (int m = 0; m < 4; m++)
#pragma unroll
                    for (int n = 0; n < 4; n++) {
                        int q = wrow * 64 + m * 16 + l4 * 4;
                        int sloc = (wcol & 1) * 64 + n * 16 + l15;
#pragma unroll
                        for (int r4 = 0; r4 < 4; r4++) {
                            u16 v = f2bf(exp2f(acc[m][n][r4] * sl2));
                            int qq = q + r4;
                            *(u16*)((char*)sP + ((qq * 256 + sloc * 2) ^ ((qq & 7) << 4))) = v;
                        }
                    }
            }
            asm volatile("s_waitcnt lgkmcnt(0)" ::: "memory");
            __builtin_amdgcn_sched_barrier(0);
            __builtin_amdgcn_s_barrier();
            __builtin_amdgcn_sched_barrier(0);

            // mass-GEMM over this s-half: macc += expP @ onehot(labels)
#pragma unroll
            for (int kg = 0; kg < 4; ++kg) {
                int labk[8];
#pragma unroll
                for (int j = 0; j < 8; j++)
                    labk[j] = slabAll[st * BS + hf * 128 + kg * 32 + l4 * 8 + j];
                bf16x8 ap[4];
#pragma unroll
                for (int m = 0; m < 4; m++) {
                    int r = h * 64 + m * 16 + l15;
                    ap[m] = *(const bf16x8*)((const char*)sP +
                                             ((r * 256 + kg * 64 + l4 * 16) ^ ((r & 7) << 4)));
                }
#pragma unroll
                for (int n = 0; n < 4; n++) {
                    int c = c0 + n * 16 + l15;
                    bf16x8 bo;
#pragma unroll
                    for (int j = 0; j < 8; j++) bo[j] = (labk[j] == c) ? (short)0x3F80 : (short)0;
                    macc[0][n] = __builtin_amdgcn_mfma_f32_16x16x32_bf16(ap[0], bo, macc[0][n], 0, 0, 0);
                    macc[1][n] = __builtin_amdgcn_mfma_f32_16x16x32_bf16(ap[1], bo, macc[1][n], 0, 0, 0);
                    macc[2][n] = __builtin_amdgcn_mfma_f32_16x16x32_bf16(ap[2], bo, macc[2][n], 0, 0, 0);
                    macc[3][n] = __builtin_amdgcn_mfma_f32_16x16x32_bf16(ap[3], bo, macc[3][n], 0, 0, 0);
                }
            }
            __builtin_amdgcn_s_barrier();   // sP reads done before rewrite / next tile
        }
    }

    // ---- flush mass to global (NS adds per cell) ----
#pragma unroll
    for (int m = 0; m < 4; m++)
#pragma unroll
        for (int n = 0; n < 4; n++) {
            int c = c0 + n * 16 + l15;
#pragma unroll
            for (int r4 = 0; r4 < 4; r4++) {
                int q = qbase + h * 64 + m * 16 + l4 * 4 + r4;
                unsafeAtomicAdd(&massp[(size_t)q * C_N + c], macc[m][n][r4]);
            }
        }
}

// ---- finalize: normalize mass, log, prior, softmax ----
__global__ void k_final(const float* __restrict__ massp, const int* __restrict__ counts,
                        const float* __restrict__ cp_p, float* __restrict__ out) {
    __shared__ float sh[4];
    int q = blockIdx.x, c = threadIdx.x;
    float m = massp[(size_t)q * C_N + c];
    float denom = blkSum(m, sh);
    float cp = *cp_p;
    float logit = logf(fmaxf(m / denom, 1e-8f)) + cp * logf(fmaxf((float)counts[c], 1.f));
    float mx = blkMax(logit, sh);
    float e = __expf(logit - mx);
    float se = blkSum(e, sh);
    out[(size_t)q * C_N + c] = logit;
    out[(size_t)Q_N * C_N + C_N + (size_t)q * C_N + c] = e / se;
    if (q == 0) out[(size_t)Q_N * C_N + c] = (float)c;
}

extern "C" void kernel_launch(void* const* d_in, const int* in_sizes, int n_in,
                              void* d_out, int out_size, void* d_ws, size_t ws_size,
                              hipStream_t stream) {
    const float* sup = (const float*)d_in[0];
    const int* lab = (const int*)d_in[1];
    const float* qry = (const float*)d_in[2];
    const float* ls = (const float*)d_in[3];
    const float* cp = (const float*)d_in[4];
    float* out = (float*)d_out;
    char* ws = (char*)d_ws;

    float* massp = (float*)(ws + WS_MASSP);
    float* mu = (float*)(ws + WS_MU);
    int* counts = (int*)(ws + WS_COUNTS);
    float* norms = (float*)(ws + WS_NORMS);
    float* colpart = (float*)(ws + WS_COLPART);
    u16* suppb = (u16*)(ws + WS_SUPPB);
    u16* qb = (u16*)(ws + WS_QB);

    hipMemsetAsync(massp, 0, Q_N * C_N * sizeof(float), stream);
    hipMemsetAsync(counts, 0, C_N * sizeof(int), stream);
    k_prep<<<S_N / 64, 256, 0, stream>>>(sup, lab, colpart, norms, counts);
    k_mu<<<D_N / 256, 256, 0, stream>>>(colpart, mu);
    k_suptrans<<<S_N, 256, 0, stream>>>(sup, norms, mu, suppb);
    k_qtrans<<<Q_N, 256, 0, stream>>>(qry, mu, qb);
    k_mass<<<(Q_N / BQ) * NS, NTHR, 0, stream>>>(qb, suppb, lab, ls, massp);
    k_final<<<Q_N, 256, 0, stream>>>(massp, counts, cp, out);
}

// Round 6
// 432.958 us; speedup vs baseline: 1.7114x; 1.7114x over previous
//
#include <hip/hip_runtime.h>
#include <math.h>

typedef unsigned short u16;
typedef unsigned char u8;
typedef __attribute__((ext_vector_type(8))) short bf16x8;
typedef __attribute__((ext_vector_type(4))) float f32x4;

#define S_N 16384
#define Q_N 4096
#define D_N 1024
#define C_N 256
#define NS 16
#define BQ 128
#define BS 128
#define BK 64
#define SRANGE (S_N / NS)     // 1024
#define NTILES (SRANGE / BS)  // 8
#define NKC (D_N / BK)        // 16
#define NTHR 512

// ---- workspace layout (bytes) ----
#define WS_MASSP   0u                                    // Q*C*4 = 4 MB
#define WS_MU      (WS_MASSP + 4194304u)                 // D*4
#define WS_COUNTS  (WS_MU + 4096u)                       // C*4
#define WS_NORMS   (WS_COUNTS + 1024u)                   // S*4
#define WS_COLPART (WS_NORMS + 65536u)                   // 256*D*4 = 1 MB
#define WS_SUPPB   (WS_COLPART + 1048576u)               // S*D*1 = 16 MB (fp8)
#define WS_QB      (WS_SUPPB + 16777216u)                // Q*D*1 = 4 MB (fp8)

#define GLOAD16(g, l)                                                        \
    __builtin_amdgcn_global_load_lds(                                        \
        (const __attribute__((address_space(1))) void*)(g),                  \
        (__attribute__((address_space(3))) void*)(l), 16, 0, 0)

// 4 floats -> 4 packed fp8 e4m3 (OCP on gfx950), RNE hardware cvt
__device__ __forceinline__ unsigned f2fp8x4(float a, float b, float c, float d) {
    unsigned v = __builtin_amdgcn_cvt_pk_fp8_f32(a, b, 0, false);
    v = __builtin_amdgcn_cvt_pk_fp8_f32(c, d, v, true);
    return v;
}

__device__ __forceinline__ u16 f2bf(float f) {
    unsigned x = __float_as_uint(f);
    return (u16)((x + 0x7fffu + ((x >> 16) & 1u)) >> 16);
}

__device__ __forceinline__ float blkSum(float v, float* sh) {
#pragma unroll
    for (int o = 32; o; o >>= 1) v += __shfl_down(v, o);
    if ((threadIdx.x & 63) == 0) sh[threadIdx.x >> 6] = v;
    __syncthreads();
    float r = sh[0] + sh[1] + sh[2] + sh[3];
    __syncthreads();
    return r;
}

__device__ __forceinline__ float blkMax(float v, float* sh) {
#pragma unroll
    for (int o = 32; o; o >>= 1) v = fmaxf(v, __shfl_down(v, o));
    if ((threadIdx.x & 63) == 0) sh[threadIdx.x >> 6] = v;
    __syncthreads();
    float r = fmaxf(fmaxf(sh[0], sh[1]), fmaxf(sh[2], sh[3]));
    __syncthreads();
    return r;
}

// ---- row L2 norms of raw support ----
__global__ void k_norms(const float* __restrict__ sup, float* __restrict__ norms) {
    int lane = threadIdx.x & 63, w = threadIdx.x >> 6;
    int row = blockIdx.x * 4 + w;
    const float4* rp = (const float4*)(sup + (size_t)row * D_N);
    float ss = 0.f;
#pragma unroll
    for (int i = 0; i < 4; i++) {
        float4 v = rp[lane + 64 * i];
        ss += v.x * v.x + v.y * v.y + v.z * v.z + v.w * v.w;
    }
#pragma unroll
    for (int o = 32; o; o >>= 1) ss += __shfl_down(ss, o);
    if (lane == 0) norms[row] = sqrtf(ss);
}

// ---- partial column sums of normalized support (64 rows per block) ----
__global__ void k_colpart(const float* __restrict__ sup, const float* __restrict__ norms,
                          float* __restrict__ colpart) {
    int rc = blockIdx.x >> 2, cg = blockIdx.x & 3;
    int c = cg * 256 + threadIdx.x;
    int r0 = rc * 64;
    float acc = 0.f;
#pragma unroll 4
    for (int i = 0; i < 64; i++) {
        int r = r0 + i;
        float inv = 1.f / fmaxf(norms[r], 1e-8f);
        acc += sup[(size_t)r * D_N + c] * inv;
    }
    colpart[rc * D_N + c] = acc;
}

// ---- reduce 256 partials -> mu ----
__global__ void k_mu(const float* __restrict__ colpart, float* __restrict__ mu) {
    int c = blockIdx.x * 256 + threadIdx.x;
    float s = 0.f;
#pragma unroll 8
    for (int i = 0; i < 256; i++) s += colpart[(size_t)i * D_N + c];
    mu[c] = s * (1.f / (float)S_N);
}

// ---- support: normalize, center, renormalize, -> fp8 x16 ----
__global__ void k_suptrans(const float* __restrict__ sup, const float* __restrict__ norms,
                           const float* __restrict__ mu, u8* __restrict__ outb) {
    __shared__ float sh[4];
    int r = blockIdx.x, t = threadIdx.x;
    float inv = 1.f / fmaxf(norms[r], 1e-8f);
    float4 x = ((const float4*)(sup + (size_t)r * D_N))[t];
    float4 m = ((const float4*)mu)[t];
    float4 y;
    y.x = x.x * inv - m.x; y.y = x.y * inv - m.y;
    y.z = x.z * inv - m.z; y.w = x.w * inv - m.w;
    float ss = y.x * y.x + y.y * y.y + y.z * y.z + y.w * y.w;
    float tot = blkSum(ss, sh);
    float s16 = 16.f / fmaxf(sqrtf(tot), 1e-8f);   // x16: center fp8 range
    ((unsigned*)(outb + (size_t)r * D_N))[t] =
        f2fp8x4(y.x * s16, y.y * s16, y.z * s16, y.w * s16);
}

// ---- query: normalize, center, renormalize, -> fp8 x16 ----
__global__ void k_qtrans(const float* __restrict__ qry, const float* __restrict__ mu,
                         u8* __restrict__ outb) {
    __shared__ float sh[4];
    int r = blockIdx.x, t = threadIdx.x;
    float4 x = ((const float4*)(qry + (size_t)r * D_N))[t];
    float ss1 = x.x * x.x + x.y * x.y + x.z * x.z + x.w * x.w;
    float tot1 = blkSum(ss1, sh);
    float inv1 = 1.f / fmaxf(sqrtf(tot1), 1e-8f);
    float4 m = ((const float4*)mu)[t];
    float4 y;
    y.x = x.x * inv1 - m.x; y.y = x.y * inv1 - m.y;
    y.z = x.z * inv1 - m.z; y.w = x.w * inv1 - m.w;
    float ss2 = y.x * y.x + y.y * y.y + y.z * y.z + y.w * y.w;
    float tot2 = blkSum(ss2, sh);
    float s16 = 16.f / fmaxf(sqrtf(tot2), 1e-8f);
    ((unsigned*)(outb + (size_t)r * D_N))[t] =
        f2fp8x4(y.x * s16, y.y * s16, y.z * s16, y.w * s16);
}

// ---- label histogram ----
__global__ void k_counts(const int* __restrict__ lab, int* __restrict__ counts) {
    int i = blockIdx.x * 256 + threadIdx.x;
    if (i < S_N) atomicAdd(&counts[lab[i]], 1);
}

// ---- main: fp8 pipelined sims-GEMM + exp(bf16 sP) + mass-GEMM vs one-hot ----
__launch_bounds__(NTHR, 2)
__global__ void k_mass(const u8* __restrict__ Qb, const u8* __restrict__ Sb,
                       const int* __restrict__ lab, const float* __restrict__ scale_p,
                       float* __restrict__ massp) {
    __shared__ u8 sQ[2][BQ * BK];     // 2x8 KB, linear-written, content chunk-swizzled
    __shared__ u8 sS[2][BS * BK];     // 2x8 KB
    __shared__ u16 sP[BQ * BS];       // 32 KB, exp(P) bf16, swizzled
    __shared__ int slabAll[SRANGE];   // 4 KB

    const int t = threadIdx.x;
    const int lane = t & 63, w = t >> 6;
    const int wrow = w >> 1, wcol = w & 1;      // sims wave grid 4x2 (per-wave 32q x 64s)
    const int l15 = lane & 15, l4 = lane >> 4;
    const int sblk = blockIdx.x >> 5;           // R4 mapping (measured-best locality)
    const int qblk = blockIdx.x & 31;
    const int qbase = qblk * BQ;
    const int s0 = sblk * SRANGE;

    const float scale = fminf(fmaxf(*scale_p, 1.f), 20.f);
    const float sl2 = scale * 1.44269504f * (1.f / 256.f);  // /256 undoes the x16*x16

    // staging: thread t stages LDS bytes [t*16,t*16+16) (linear);
    // row = t>>2, source 16B-chunk pre-swizzled: q ^= (row>>1)&3  (rule 21)
    const int srow = t >> 2;
    const int sck = (t & 3) ^ ((srow >> 1) & 3);
    const int lofs = w * 1024;

    // fragment read offsets: granule g = k2*4+l4 (8B units), chunk-XOR swizzle
    int aoff[2][2], boff[4][2];
#pragma unroll
    for (int m = 0; m < 2; m++)
#pragma unroll
        for (int k2 = 0; k2 < 2; k2++) {
            int r = wrow * 32 + m * 16 + l15;
            int g = k2 * 4 + l4;
            aoff[m][k2] = r * 64 + ((((g >> 1) ^ ((r >> 1) & 3)) << 4) | ((g & 1) << 3));
        }
#pragma unroll
    for (int n = 0; n < 4; n++)
#pragma unroll
        for (int k2 = 0; k2 < 2; k2++) {
            int r = wcol * 64 + n * 16 + l15;
            int g = k2 * 4 + l4;
            boff[n][k2] = r * 64 + ((((g >> 1) ^ ((r >> 1) & 3)) << 4) | ((g & 1) << 3));
        }

    auto stage = [&](int sbase, int kc, int buf) {
        const u8* gq = Qb + (size_t)(qbase + srow) * D_N + kc * BK + sck * 16;
        const u8* gs = Sb + (size_t)(sbase + srow) * D_N + kc * BK + sck * 16;
        GLOAD16(gq, (char*)sQ[buf] + lofs);
        GLOAD16(gs, (char*)sS[buf] + lofs);
    };

    // slab first, then clean drain so pipeline vmcnt counts are exact
    for (int i = t; i < SRANGE; i += NTHR) slabAll[i] = lab[s0 + i];
    asm volatile("s_waitcnt vmcnt(0) lgkmcnt(0)" ::: "memory");
    __builtin_amdgcn_s_barrier();

    // mass accumulator: wave covers (h*64 q-rows) x (64 c-cols)
    const int h = w >> 2;
    const int c0 = (w & 3) * 64;
    f32x4 macc[4][4];
#pragma unroll
    for (int m = 0; m < 4; m++)
#pragma unroll
        for (int n = 0; n < 4; n++) macc[m][n] = (f32x4){0.f, 0.f, 0.f, 0.f};

    stage(s0, 0, 0);   // prologue: chunk 0 -> buf 0 (2 loads in flight)

    for (int st = 0; st < NTILES; ++st) {
        const int sbase = s0 + st * BS;
        f32x4 acc[2][4];
#pragma unroll
        for (int m = 0; m < 2; m++)
#pragma unroll
            for (int n = 0; n < 4; n++) acc[m][n] = (f32x4){0.f, 0.f, 0.f, 0.f};

        for (int kc = 0; kc < NKC; ++kc) {
            const int buf = kc & 1;
            int nkc = kc + 1, nsb = sbase;
            if (nkc == NKC) { nkc = 0; nsb = (st + 1 < NTILES) ? sbase + BS : sbase; }
            stage(nsb, nkc, buf ^ 1);                         // 4 outstanding
            asm volatile("s_waitcnt vmcnt(2)" ::: "memory");  // current chunk resident
            __builtin_amdgcn_s_barrier();                     // no drain: next 2 in flight
            __builtin_amdgcn_sched_barrier(0);

            const char* bq = (const char*)sQ[buf];
            const char* bs = (const char*)sS[buf];
            __builtin_amdgcn_s_setprio(1);
#pragma unroll
            for (int k2 = 0; k2 < 2; k2++) {
                long long a0 = *(const long long*)(bq + aoff[0][k2]);
                long long a1 = *(const long long*)(bq + aoff[1][k2]);
                long long b0 = *(const long long*)(bs + boff[0][k2]);
                long long b1 = *(const long long*)(bs + boff[1][k2]);
                long long b2 = *(const long long*)(bs + boff[2][k2]);
                long long b3 = *(const long long*)(bs + boff[3][k2]);
                acc[0][0] = __builtin_amdgcn_mfma_f32_16x16x32_fp8_fp8(a0, b0, acc[0][0], 0, 0, 0);
                acc[0][1] = __builtin_amdgcn_mfma_f32_16x16x32_fp8_fp8(a0, b1, acc[0][1], 0, 0, 0);
                acc[0][2] = __builtin_amdgcn_mfma_f32_16x16x32_fp8_fp8(a0, b2, acc[0][2], 0, 0, 0);
                acc[0][3] = __builtin_amdgcn_mfma_f32_16x16x32_fp8_fp8(a0, b3, acc[0][3], 0, 0, 0);
                acc[1][0] = __builtin_amdgcn_mfma_f32_16x16x32_fp8_fp8(a1, b0, acc[1][0], 0, 0, 0);
                acc[1][1] = __builtin_amdgcn_mfma_f32_16x16x32_fp8_fp8(a1, b1, acc[1][1], 0, 0, 0);
                acc[1][2] = __builtin_amdgcn_mfma_f32_16x16x32_fp8_fp8(a1, b2, acc[1][2], 0, 0, 0);
                acc[1][3] = __builtin_amdgcn_mfma_f32_16x16x32_fp8_fp8(a1, b3, acc[1][3], 0, 0, 0);
            }
            __builtin_amdgcn_s_setprio(0);
            __builtin_amdgcn_sched_barrier(0);
            __builtin_amdgcn_s_barrier();   // readers done; buf becomes prefetch target
        }

        // ---- exp2(P*scale*log2e/256) -> bf16 -> sP (swizzled [q][s]) ----
#pragma unroll
        for (int m = 0; m < 2; m++)
#pragma unroll
            for (int n = 0; n < 4; n++) {
                int q = wrow * 32 + m * 16 + l4 * 4;
                int s = wcol * 64 + n * 16 + l15;
#pragma unroll
                for (int r4 = 0; r4 < 4; r4++) {
                    u16 v = f2bf(exp2f(acc[m][n][r4] * sl2));
                    int qq = q + r4;
                    *(u16*)((char*)sP + (((qq * 256) + s * 2) ^ ((qq & 7) << 4))) = v;
                }
            }
        asm volatile("s_waitcnt lgkmcnt(0)" ::: "memory");
        __builtin_amdgcn_sched_barrier(0);
        __builtin_amdgcn_s_barrier();

        // ---- mass-GEMM: macc += expP @ onehot(labels), bf16 ----
#pragma unroll
        for (int kg = 0; kg < 4; ++kg) {
            int labk[8];
#pragma unroll
            for (int j = 0; j < 8; j++) labk[j] = slabAll[st * BS + kg * 32 + l4 * 8 + j];
            bf16x8 ap[4];
#pragma unroll
            for (int m = 0; m < 4; m++) {
                int r = h * 64 + m * 16 + l15;
                ap[m] = *(const bf16x8*)((const char*)sP +
                                         ((r * 256 + kg * 64 + l4 * 16) ^ ((r & 7) << 4)));
            }
#pragma unroll
            for (int n = 0; n < 4; n++) {
                int c = c0 + n * 16 + l15;
                bf16x8 bo;
#pragma unroll
                for (int j = 0; j < 8; j++) bo[j] = (labk[j] == c) ? (short)0x3F80 : (short)0;
                macc[0][n] = __builtin_amdgcn_mfma_f32_16x16x32_bf16(ap[0], bo, macc[0][n], 0, 0, 0);
                macc[1][n] = __builtin_amdgcn_mfma_f32_16x16x32_bf16(ap[1], bo, macc[1][n], 0, 0, 0);
                macc[2][n] = __builtin_amdgcn_mfma_f32_16x16x32_bf16(ap[2], bo, macc[2][n], 0, 0, 0);
                macc[3][n] = __builtin_amdgcn_mfma_f32_16x16x32_bf16(ap[3], bo, macc[3][n], 0, 0, 0);
            }
        }
        // sP rewritten only deep into next tile's kc loop -> safe
    }

    // ---- flush mass to global (NS adds per cell) ----
#pragma unroll
    for (int m = 0; m < 4; m++)
#pragma unroll
        for (int n = 0; n < 4; n++) {
            int c = c0 + n * 16 + l15;
#pragma unroll
            for (int r4 = 0; r4 < 4; r4++) {
                int q = qbase + h * 64 + m * 16 + l4 * 4 + r4;
                unsafeAtomicAdd(&massp[(size_t)q * C_N + c], macc[m][n][r4]);
            }
        }
}

// ---- finalize: normalize mass, log, prior, softmax ----
__global__ void k_final(const float* __restrict__ massp, const int* __restrict__ counts,
                        const float* __restrict__ cp_p, float* __restrict__ out) {
    __shared__ float sh[4];
    int q = blockIdx.x, c = threadIdx.x;
    float m = massp[(size_t)q * C_N + c];
    float denom = blkSum(m, sh);
    float cp = *cp_p;
    float logit = logf(fmaxf(m / denom, 1e-8f)) + cp * logf(fmaxf((float)counts[c], 1.f));
    float mx = blkMax(logit, sh);
    float e = __expf(logit - mx);
    float se = blkSum(e, sh);
    out[(size_t)q * C_N + c] = logit;
    out[(size_t)Q_N * C_N + C_N + (size_t)q * C_N + c] = e / se;
    if (q == 0) out[(size_t)Q_N * C_N + c] = (float)c;
}

extern "C" void kernel_launch(void* const* d_in, const int* in_sizes, int n_in,
                              void* d_out, int out_size, void* d_ws, size_t ws_size,
                              hipStream_t stream) {
    const float* sup = (const float*)d_in[0];
    const int* lab = (const int*)d_in[1];
    const float* qry = (const float*)d_in[2];
    const float* ls = (const float*)d_in[3];
    const float* cp = (const float*)d_in[4];
    float* out = (float*)d_out;
    char* ws = (char*)d_ws;

    float* massp = (float*)(ws + WS_MASSP);
    float* mu = (float*)(ws + WS_MU);
    int* counts = (int*)(ws + WS_COUNTS);
    float* norms = (float*)(ws + WS_NORMS);
    float* colpart = (float*)(ws + WS_COLPART);
    u8* suppb = (u8*)(ws + WS_SUPPB);
    u8* qb = (u8*)(ws + WS_QB);

    hipMemsetAsync(massp, 0, Q_N * C_N * sizeof(float), stream);
    hipMemsetAsync(counts, 0, C_N * sizeof(int), stream);
    k_norms<<<S_N / 4, 256, 0, stream>>>(sup, norms);
    k_colpart<<<1024, 256, 0, stream>>>(sup, norms, colpart);
    k_mu<<<D_N / 256, 256, 0, stream>>>(colpart, mu);
    k_suptrans<<<S_N, 256, 0, stream>>>(sup, norms, mu, suppb);
    k_qtrans<<<Q_N, 256, 0, stream>>>(qry, mu, qb);
    k_counts<<<S_N / 256, 256, 0, stream>>>(lab, counts);
    k_mass<<<(Q_N / BQ) * NS, NTHR, 0, stream>>>(qb, suppb, lab, ls, massp);
    k_final<<<Q_N, 256, 0, stream>>>(massp, counts, cp, out);
}